// Round 1
// baseline (556.488 us; speedup 1.0000x reference)
//
#include <hip/hip_runtime.h>
#include <math.h>

typedef __attribute__((ext_vector_type(8))) short short8;
typedef __attribute__((ext_vector_type(4))) float f32x4;

__device__ __forceinline__ float b2f(short s){
  return __uint_as_float(((unsigned int)(unsigned short)s) << 16);
}
__device__ __forceinline__ short f2b(float f){
  unsigned int u = __float_as_uint(f);
  u = (u + 0x7fffu + ((u >> 16) & 1u)) >> 16;
  return (short)u;
}

// ---------------- weight f32 -> bf16 conversion ----------------
__global__ __launch_bounds__(256) void cvt_w(
    const float* __restrict__ s0, const float* __restrict__ s1,
    const float* __restrict__ s2, const float* __restrict__ s3,
    const float* __restrict__ s4, const float* __restrict__ s5,
    short* __restrict__ dst)
{
  const float* srcs[6] = {s0, s1, s2, s3, s4, s5};
  int i = blockIdx.x * 256 + threadIdx.x;       // 6*65536 total
  dst[i] = f2b(srcs[i >> 16][i & 65535]);
}

// ---------------- LayerNorm: f32 in, bf16 out ----------------
__global__ __launch_bounds__(256) void ln_k(
    const float* __restrict__ x, const float* __restrict__ g,
    const float* __restrict__ bta, short* __restrict__ y)
{
  const int row = blockIdx.x, t = threadIdx.x;
  const size_t base = (size_t)row * 256;
  float v = x[base + t];
  float s1 = v, s2 = v * v;
  #pragma unroll
  for (int off = 32; off; off >>= 1){ s1 += __shfl_down(s1, off); s2 += __shfl_down(s2, off); }
  __shared__ float a1[4], a2[4];
  __shared__ float mu_s, rs_s;
  if ((t & 63) == 0){ a1[t >> 6] = s1; a2[t >> 6] = s2; }
  __syncthreads();
  if (t == 0){
    float S1 = a1[0] + a1[1] + a1[2] + a1[3];
    float S2 = a2[0] + a2[1] + a2[2] + a2[3];
    float mu = S1 * 0.00390625f;
    float var = S2 * 0.00390625f - mu * mu;
    mu_s = mu; rs_s = rsqrtf(var + 1e-5f);
  }
  __syncthreads();
  y[base + t] = f2b((v - mu_s) * rs_s * g[t] + bta[t]);
}

// ---------------- GEMM: C[M,256] = A[M,256] @ W[256,256]^T + b ----------------
// A, W bf16 (W in [N][K] layout = exactly W as given). f32 accum via MFMA.
// Epilogue: optional exact GELU, optional f32 residual add, f32 and/or bf16 out.
template<int RES, int GELU, int OF, int OB>
__global__ __launch_bounds__(256) void gemm256(
    const short* __restrict__ A, const short* __restrict__ W,
    const float* __restrict__ bias, const float* __restrict__ res,
    float* __restrict__ outF, short* __restrict__ outB)
{
  __shared__ short As[64][48];   // pad to 48 (96B rows, 16B aligned)
  __shared__ short Ws[64][48];
  const int tid = threadIdx.x;
  const int m0 = blockIdx.x << 6;
  const int n0 = blockIdx.y << 6;
  const int wave = tid >> 6, lane = tid & 63;
  const int sr = tid >> 2, sc = (tid & 3) << 3;
  const int fr = lane & 15, fk = (lane >> 4) << 3;
  f32x4 acc[4] = {{0,0,0,0},{0,0,0,0},{0,0,0,0},{0,0,0,0}};
  for (int k0 = 0; k0 < 256; k0 += 32){
    if (k0) __syncthreads();
    *(short8*)&As[sr][sc] = *(const short8*)&A[(size_t)(m0 + sr) * 256 + k0 + sc];
    *(short8*)&Ws[sr][sc] = *(const short8*)&W[(size_t)(n0 + sr) * 256 + k0 + sc];
    __syncthreads();
    short8 af = *(const short8*)&As[(wave << 4) + fr][fk];
    #pragma unroll
    for (int nt = 0; nt < 4; ++nt){
      short8 bf = *(const short8*)&Ws[(nt << 4) + fr][fk];
      acc[nt] = __builtin_amdgcn_mfma_f32_16x16x32_bf16(af, bf, acc[nt], 0, 0, 0);
    }
  }
  const int r0 = (wave << 4) + ((lane >> 4) << 2);
  #pragma unroll
  for (int nt = 0; nt < 4; ++nt){
    const int n = n0 + (nt << 4) + fr;
    const float bv = bias[n];
    #pragma unroll
    for (int r = 0; r < 4; ++r){
      const size_t idx = (size_t)(m0 + r0 + r) * 256 + n;
      float v = acc[nt][r] + bv;
      if (GELU) v = 0.5f * v * (1.0f + erff(v * 0.70710678118f));
      if (RES) v += res[idx];
      if (OF) outF[idx] = v;
      if (OB) outB[idx] = f2b(v);
    }
  }
}

// ---------------- fused attention ----------------
// Per block: 32 q-rows, all 4 heads. Q/K/V bf16 in [*, 256] GEMM layout.
// scores = QK^T/8 + cw ; softmax ; ctx = P V ; am = mean_h P.
__global__ __launch_bounds__(512) void attn_k(
    const short* __restrict__ Qb, const short* __restrict__ Kb,
    const short* __restrict__ Vb, const float* __restrict__ cw,
    short* __restrict__ ctx, float* __restrict__ am_out)
{
  __shared__ float KVs[256][65];    // K_h then V_h, stride 65 (conflict-free)
  __shared__ float Qs[32][64];
  __shared__ float pbuf[32][256];
  const int b = blockIdx.y;
  const int q0 = blockIdx.x << 5;
  const int tid = threadIdx.x;
  const int wave = tid >> 6, lane = tid & 63;
  const int wr0 = wave << 2;        // this wave's first row within tile

  float cwv[4][4], am[4][4];
  #pragma unroll
  for (int r = 0; r < 4; ++r){
    const size_t rowb = ((size_t)b * 4096 + q0 + wr0 + r) * 256;
    #pragma unroll
    for (int jb = 0; jb < 4; ++jb){ cwv[r][jb] = cw[rowb + (jb << 6) + lane]; am[r][jb] = 0.f; }
  }

  for (int h = 0; h < 4; ++h){
    __syncthreads();
    // stage K_h -> KVs (f32)
    #pragma unroll
    for (int it = 0; it < 4; ++it){
      int idx = tid + (it << 9);
      int j = idx >> 3, d0 = (idx & 7) << 3;
      short8 kv = *(const short8*)&Kb[((size_t)(b * 256 + j) << 8) + (h << 6) + d0];
      #pragma unroll
      for (int e = 0; e < 8; ++e) KVs[j][d0 + e] = b2f(kv[e]);
    }
    // stage Q_h
    #pragma unroll
    for (int it = 0; it < 4; ++it){
      int idx = tid + (it << 9);
      int r = idx >> 6, d = idx & 63;
      Qs[r][d] = b2f(Qb[((size_t)(b * 4096 + q0 + r) << 8) + (h << 6) + d]);
    }
    __syncthreads();
    // scores + softmax (wave owns 4 rows; lane owns kv j = jb*64+lane)
    #pragma unroll
    for (int r = 0; r < 4; ++r){
      const float* q = Qs[wr0 + r];
      const float* k0p = &KVs[lane][0];
      const float* k1p = &KVs[64 + lane][0];
      const float* k2p = &KVs[128 + lane][0];
      const float* k3p = &KVs[192 + lane][0];
      float s0 = 0, s1 = 0, s2 = 0, s3 = 0;
      #pragma unroll
      for (int d = 0; d < 64; ++d){
        float qv = q[d];
        s0 += qv * k0p[d]; s1 += qv * k1p[d]; s2 += qv * k2p[d]; s3 += qv * k3p[d];
      }
      float sc0 = s0 * 0.125f + cwv[r][0];
      float sc1 = s1 * 0.125f + cwv[r][1];
      float sc2 = s2 * 0.125f + cwv[r][2];
      float sc3 = s3 * 0.125f + cwv[r][3];
      float mx = fmaxf(fmaxf(sc0, sc1), fmaxf(sc2, sc3));
      #pragma unroll
      for (int off = 32; off; off >>= 1) mx = fmaxf(mx, __shfl_xor(mx, off));
      float p0 = __expf(sc0 - mx), p1 = __expf(sc1 - mx);
      float p2 = __expf(sc2 - mx), p3 = __expf(sc3 - mx);
      float sm = p0 + p1 + p2 + p3;
      #pragma unroll
      for (int off = 32; off; off >>= 1) sm += __shfl_xor(sm, off);
      float inv = 1.0f / sm;
      p0 *= inv; p1 *= inv; p2 *= inv; p3 *= inv;
      am[r][0] += 0.25f * p0; am[r][1] += 0.25f * p1;
      am[r][2] += 0.25f * p2; am[r][3] += 0.25f * p3;
      pbuf[wr0 + r][lane] = p0;       pbuf[wr0 + r][64 + lane] = p1;
      pbuf[wr0 + r][128 + lane] = p2; pbuf[wr0 + r][192 + lane] = p3;
    }
    __syncthreads();
    // stage V_h (overwrites K_h)
    #pragma unroll
    for (int it = 0; it < 4; ++it){
      int idx = tid + (it << 9);
      int j = idx >> 3, d0 = (idx & 7) << 3;
      short8 kv = *(const short8*)&Vb[((size_t)(b * 256 + j) << 8) + (h << 6) + d0];
      #pragma unroll
      for (int e = 0; e < 8; ++e) KVs[j][d0 + e] = b2f(kv[e]);
    }
    __syncthreads();
    // ctx: o[d=lane] = sum_j p[j] * V[j][d]
    #pragma unroll
    for (int r = 0; r < 4; ++r){
      const float* pr = pbuf[wr0 + r];
      float o0 = 0, o1 = 0, o2 = 0, o3 = 0;
      #pragma unroll
      for (int j = 0; j < 256; j += 4){
        o0 += pr[j]     * KVs[j][lane];
        o1 += pr[j + 1] * KVs[j + 1][lane];
        o2 += pr[j + 2] * KVs[j + 2][lane];
        o3 += pr[j + 3] * KVs[j + 3][lane];
      }
      ctx[((size_t)(b * 4096 + q0 + wr0 + r) << 8) + (h << 6) + lane] = f2b((o0 + o1) + (o2 + o3));
    }
  }
  #pragma unroll
  for (int r = 0; r < 4; ++r){
    const size_t rowb = ((size_t)b * 4096 + q0 + wr0 + r) * 256;
    #pragma unroll
    for (int jb = 0; jb < 4; ++jb) am_out[rowb + (jb << 6) + lane] = am[r][jb];
  }
}

extern "C" void kernel_launch(void* const* d_in, const int* in_sizes, int n_in,
                              void* d_out, int out_size, void* d_ws, size_t ws_size,
                              hipStream_t stream)
{
  const float* node_emb = (const float*)d_in[0];
  const float* cluster  = (const float*)d_in[1];
  const float* cw       = (const float*)d_in[2];
  const float* ln_q_g   = (const float*)d_in[3];
  const float* ln_q_b   = (const float*)d_in[4];
  const float* ln_kv_g  = (const float*)d_in[5];
  const float* ln_kv_b  = (const float*)d_in[6];
  const float* ln_o_g   = (const float*)d_in[7];
  const float* ln_o_b   = (const float*)d_in[8];
  const float* W_q  = (const float*)d_in[9];  const float* b_q  = (const float*)d_in[10];
  const float* W_k  = (const float*)d_in[11]; const float* b_k  = (const float*)d_in[12];
  const float* W_v  = (const float*)d_in[13]; const float* b_v  = (const float*)d_in[14];
  const float* W_o  = (const float*)d_in[15]; const float* b_o  = (const float*)d_in[16];
  const float* W_m1 = (const float*)d_in[17]; const float* b_m1 = (const float*)d_in[18];
  const float* W_m2 = (const float*)d_in[19]; const float* b_m2 = (const float*)d_in[20];

  char* ws = (char*)d_ws;
  short* Wbf  = (short*)ws;                                   // 786,432 B (6 x 64K bf16)
  short* n1   = (short*)(ws + 786432);                        // 16.78 MB: q_in -> ctx -> h1
  short* n2   = (short*)(ws + 786432 + 16777216);             // 16.78 MB: Q -> h_ln
  short* kvin = (short*)(ws + 786432 + 2 * 16777216);         // 1 MB
  short* Kb   = (short*)(ws + 786432 + 2 * 16777216 + 1048576);
  short* Vb   = (short*)(ws + 786432 + 2 * 16777216 + 2 * 1048576);

  float* xbuf = (float*)d_out;            // first half: x, later overwritten by final out
  float* amof = (float*)d_out + 8388608;  // second half: attn_matrix

  cvt_w<<<1536, 256, 0, stream>>>(W_q, W_k, W_v, W_o, W_m1, W_m2, Wbf);
  ln_k<<<32768, 256, 0, stream>>>(node_emb, ln_q_g, ln_q_b, n1);
  ln_k<<<2048, 256, 0, stream>>>(cluster, ln_kv_g, ln_kv_b, kvin);
  // Q / K / V projections
  gemm256<0,0,0,1><<<dim3(512, 4), 256, 0, stream>>>(n1,   Wbf,          b_q, nullptr, nullptr, n2);
  gemm256<0,0,0,1><<<dim3(32, 4),  256, 0, stream>>>(kvin, Wbf + 65536,  b_k, nullptr, nullptr, Kb);
  gemm256<0,0,0,1><<<dim3(32, 4),  256, 0, stream>>>(kvin, Wbf + 131072, b_v, nullptr, nullptr, Vb);
  // attention (writes ctx -> n1, attn_matrix -> d_out 2nd half)
  attn_k<<<dim3(128, 8), 512, 0, stream>>>(n2, Kb, Vb, cw, n1, amof);
  // O proj + residual -> x (f32, in d_out first half)
  gemm256<1,0,1,0><<<dim3(512, 4), 256, 0, stream>>>(n1, Wbf + 196608, b_o, node_emb, xbuf, nullptr);
  // LN(x) -> h_ln (bf16 in n2)
  ln_k<<<32768, 256, 0, stream>>>(xbuf, ln_o_g, ln_o_b, n2);
  // MLP1 + GELU -> n1 ; MLP2 + residual(x) -> final out (in-place over x)
  gemm256<0,1,0,1><<<dim3(512, 4), 256, 0, stream>>>(n2, Wbf + 262144, b_m1, nullptr, nullptr, n1);
  gemm256<1,0,1,0><<<dim3(512, 4), 256, 0, stream>>>(n1, Wbf + 327680, b_m2, xbuf, xbuf, nullptr);
}

// Round 2
// 192.824 us; speedup vs baseline: 2.8860x; 2.8860x over previous
//
#include <hip/hip_runtime.h>
#include <math.h>

typedef __attribute__((ext_vector_type(8))) short short8;
typedef __attribute__((ext_vector_type(4))) float f32x4;

__device__ __forceinline__ float b2f(short s){
  return __uint_as_float(((unsigned int)(unsigned short)s) << 16);
}
__device__ __forceinline__ short f2b(float f){
  unsigned int u = __float_as_uint(f);
  u = (u + 0x7fffu + ((u >> 16) & 1u)) >> 16;
  return (short)u;
}

// ---------------- weight f32 -> bf16 conversion ----------------
__global__ __launch_bounds__(256) void cvt_w(
    const float* __restrict__ s0, const float* __restrict__ s1,
    const float* __restrict__ s2, const float* __restrict__ s3,
    const float* __restrict__ s4, const float* __restrict__ s5,
    short* __restrict__ dst)
{
  const float* srcs[6] = {s0, s1, s2, s3, s4, s5};
  int i = blockIdx.x * 256 + threadIdx.x;       // 6*65536 total
  dst[i] = f2b(srcs[i >> 16][i & 65535]);
}

// ---------------- LayerNorm: f32 in, bf16 out ----------------
__global__ __launch_bounds__(256) void ln_k(
    const float* __restrict__ x, const float* __restrict__ g,
    const float* __restrict__ bta, short* __restrict__ y)
{
  const int row = blockIdx.x, t = threadIdx.x;
  const size_t base = (size_t)row * 256;
  float v = x[base + t];
  float s1 = v, s2 = v * v;
  #pragma unroll
  for (int off = 32; off; off >>= 1){ s1 += __shfl_down(s1, off); s2 += __shfl_down(s2, off); }
  __shared__ float a1[4], a2[4];
  __shared__ float mu_s, rs_s;
  if ((t & 63) == 0){ a1[t >> 6] = s1; a2[t >> 6] = s2; }
  __syncthreads();
  if (t == 0){
    float S1 = a1[0] + a1[1] + a1[2] + a1[3];
    float S2 = a2[0] + a2[1] + a2[2] + a2[3];
    float mu = S1 * 0.00390625f;
    float var = S2 * 0.00390625f - mu * mu;
    mu_s = mu; rs_s = rsqrtf(var + 1e-5f);
  }
  __syncthreads();
  y[base + t] = f2b((v - mu_s) * rs_s * g[t] + bta[t]);
}

// ---------------- GEMM: C[M,256] = A[M,256] @ W[256,256]^T + b ----------------
// A, W bf16 (W in [N][K] layout). f32 accum via MFMA.
// Epilogue: optional GELU, f32 residual, f32/bf16 out, OT = bf16 out transposed
// into Vt layout: vt[(m&~255 | n)*256 + (m&255)]  (m = b*256+j, n = h*64+d)
template<int RES, int GELU, int OF, int OB, int OT>
__global__ __launch_bounds__(256) void gemm256(
    const short* __restrict__ A, const short* __restrict__ W,
    const float* __restrict__ bias, const float* __restrict__ res,
    float* __restrict__ outF, short* __restrict__ outB)
{
  __shared__ short As[64][48];   // pad to 48 (96B rows, 16B aligned)
  __shared__ short Ws[64][48];
  const int tid = threadIdx.x;
  const int m0 = blockIdx.x << 6;
  const int n0 = blockIdx.y << 6;
  const int wave = tid >> 6, lane = tid & 63;
  const int sr = tid >> 2, sc = (tid & 3) << 3;
  const int fr = lane & 15, fk = (lane >> 4) << 3;
  f32x4 acc[4] = {{0,0,0,0},{0,0,0,0},{0,0,0,0},{0,0,0,0}};
  for (int k0 = 0; k0 < 256; k0 += 32){
    if (k0) __syncthreads();
    *(short8*)&As[sr][sc] = *(const short8*)&A[(size_t)(m0 + sr) * 256 + k0 + sc];
    *(short8*)&Ws[sr][sc] = *(const short8*)&W[(size_t)(n0 + sr) * 256 + k0 + sc];
    __syncthreads();
    short8 af = *(const short8*)&As[(wave << 4) + fr][fk];
    #pragma unroll
    for (int nt = 0; nt < 4; ++nt){
      short8 bf = *(const short8*)&Ws[(nt << 4) + fr][fk];
      acc[nt] = __builtin_amdgcn_mfma_f32_16x16x32_bf16(af, bf, acc[nt], 0, 0, 0);
    }
  }
  const int r0 = (wave << 4) + ((lane >> 4) << 2);
  #pragma unroll
  for (int nt = 0; nt < 4; ++nt){
    const int n = n0 + (nt << 4) + fr;
    const float bv = bias[n];
    #pragma unroll
    for (int r = 0; r < 4; ++r){
      const int m = m0 + r0 + r;
      const size_t idx = (size_t)m * 256 + n;
      float v = acc[nt][r] + bv;
      if (GELU) v = 0.5f * v * (1.0f + erff(v * 0.70710678118f));
      if (RES) v += res[idx];
      if (OF) outF[idx] = v;
      if (OB){
        if (OT) outB[(size_t)((m & ~255) | n) * 256 + (m & 255)] = f2b(v);
        else    outB[idx] = f2b(v);
      }
    }
  }
}

// ---------------- fused MFMA attention ----------------
// Block: 64 q-rows, 4 waves, all 4 heads. Q [B*4096][256] bf16, K [B*256][256] bf16,
// Vt [B*256 (h*64+d)][256 (j)] bf16.  scores=QK^T/8+cw; softmax; ctx=PV; am=mean_h P.
__global__ __launch_bounds__(256, 2) void attn_k(
    const short* __restrict__ Qb, const short* __restrict__ Kb,
    const short* __restrict__ Vtg, const float* __restrict__ cw,
    short* __restrict__ ctx, float* __restrict__ am_out)
{
  __shared__ short Kp[256][72];   // K_h padded (2-way bank max); overlaid by P after scores
  __shared__ short Vt[64][264];   // Vt_h padded
  short* Pb = &Kp[0][0];          // P: 4 waves * [16][264] = 16896 shorts <= 18432

  const int b = blockIdx.y;
  const int q0 = blockIdx.x << 6;
  const int tid = threadIdx.x;
  const int w = tid >> 6, lane = tid & 63;
  const int l15 = lane & 15, g = lane >> 4;
  const size_t qbase = (size_t)b * 4096 + q0 + (w << 4);

  // clustering weights + attn_matrix accumulator in registers (C/D layout)
  float cwv[16][4], am[16][4];
  #pragma unroll
  for (int nt = 0; nt < 16; ++nt)
    #pragma unroll
    for (int r = 0; r < 4; ++r){
      cwv[nt][r] = cw[(qbase + (g << 2) + r) * 256 + (nt << 4) + l15];
      am[nt][r] = 0.f;
    }

  for (int h = 0; h < 4; ++h){
    __syncthreads();                       // prior head's PV done (Kp/P + Vt free)
    #pragma unroll
    for (int it = 0; it < 8; ++it){        // stage K_h -> Kp
      int idx = tid + (it << 8);           // 2048 chunks of 16B
      int row = idx >> 3, c0 = (idx & 7) << 3;
      *(short8*)&Kp[row][c0] = *(const short8*)&Kb[((size_t)(b * 256 + row) << 8) + (h << 6) + c0];
    }
    #pragma unroll
    for (int it = 0; it < 8; ++it){        // stage Vt_h -> Vt
      int idx = tid + (it << 8);
      int row = idx >> 5, c0 = (idx & 31) << 3;
      *(short8*)&Vt[row][c0] = *(const short8*)&Vtg[((size_t)(b * 256 + (h << 6) + row) << 8) + c0];
    }
    // Q A-fragments straight from global (L2)
    short8 af0 = *(const short8*)&Qb[(qbase + l15) * 256 + (h << 6) + (g << 3)];
    short8 af1 = *(const short8*)&Qb[(qbase + l15) * 256 + (h << 6) + 32 + (g << 3)];
    __syncthreads();

    // ---- scores: S[16 x 256] per wave ----
    f32x4 acc[16];
    #pragma unroll
    for (int nt = 0; nt < 16; ++nt) acc[nt] = {0,0,0,0};
    #pragma unroll
    for (int nt = 0; nt < 16; ++nt){
      short8 bf0 = *(const short8*)&Kp[(nt << 4) + l15][(g << 3)];
      acc[nt] = __builtin_amdgcn_mfma_f32_16x16x32_bf16(af0, bf0, acc[nt], 0, 0, 0);
      short8 bf1 = *(const short8*)&Kp[(nt << 4) + l15][32 + (g << 3)];
      acc[nt] = __builtin_amdgcn_mfma_f32_16x16x32_bf16(af1, bf1, acc[nt], 0, 0, 0);
    }
    // ---- softmax in registers (row = (g<<2)+r, owned by the 16 lanes sharing g) ----
    #pragma unroll
    for (int r = 0; r < 4; ++r){
      #pragma unroll
      for (int nt = 0; nt < 16; ++nt)
        acc[nt][r] = acc[nt][r] * 0.125f + cwv[nt][r];
      float m = acc[0][r];
      #pragma unroll
      for (int nt = 1; nt < 16; ++nt) m = fmaxf(m, acc[nt][r]);
      #pragma unroll
      for (int off = 8; off; off >>= 1) m = fmaxf(m, __shfl_xor(m, off));
      float s = 0.f;
      #pragma unroll
      for (int nt = 0; nt < 16; ++nt){ acc[nt][r] = __expf(acc[nt][r] - m); s += acc[nt][r]; }
      #pragma unroll
      for (int off = 8; off; off >>= 1) s += __shfl_xor(s, off);
      float inv = 1.f / s;
      #pragma unroll
      for (int nt = 0; nt < 16; ++nt){ acc[nt][r] *= inv; am[nt][r] += 0.25f * acc[nt][r]; }
    }
    __syncthreads();                       // all waves done reading Kp
    // ---- P (bf16) -> LDS over Kp region ----
    #pragma unroll
    for (int nt = 0; nt < 16; ++nt)
      #pragma unroll
      for (int r = 0; r < 4; ++r)
        Pb[((w << 4) + (g << 2) + r) * 264 + (nt << 4) + l15] = f2b(acc[nt][r]);
    __syncthreads();
    // ---- ctx = P @ V  (A = P rows, B = Vt rows) ----
    f32x4 oc[4] = {{0,0,0,0},{0,0,0,0},{0,0,0,0},{0,0,0,0}};
    #pragma unroll
    for (int kk = 0; kk < 8; ++kk){
      short8 pa = *(const short8*)&Pb[((w << 4) + l15) * 264 + (kk << 5) + (g << 3)];
      #pragma unroll
      for (int n2 = 0; n2 < 4; ++n2){
        short8 vb = *(const short8*)&Vt[(n2 << 4) + l15][(kk << 5) + (g << 3)];
        oc[n2] = __builtin_amdgcn_mfma_f32_16x16x32_bf16(pa, vb, oc[n2], 0, 0, 0);
      }
    }
    #pragma unroll
    for (int n2 = 0; n2 < 4; ++n2)
      #pragma unroll
      for (int r = 0; r < 4; ++r)
        ctx[(qbase + (g << 2) + r) * 256 + (h << 6) + (n2 << 4) + l15] = f2b(oc[n2][r]);
  }
  #pragma unroll
  for (int nt = 0; nt < 16; ++nt)
    #pragma unroll
    for (int r = 0; r < 4; ++r)
      am_out[(qbase + (g << 2) + r) * 256 + (nt << 4) + l15] = am[nt][r];
}

extern "C" void kernel_launch(void* const* d_in, const int* in_sizes, int n_in,
                              void* d_out, int out_size, void* d_ws, size_t ws_size,
                              hipStream_t stream)
{
  const float* node_emb = (const float*)d_in[0];
  const float* cluster  = (const float*)d_in[1];
  const float* cw       = (const float*)d_in[2];
  const float* ln_q_g   = (const float*)d_in[3];
  const float* ln_q_b   = (const float*)d_in[4];
  const float* ln_kv_g  = (const float*)d_in[5];
  const float* ln_kv_b  = (const float*)d_in[6];
  const float* ln_o_g   = (const float*)d_in[7];
  const float* ln_o_b   = (const float*)d_in[8];
  const float* W_q  = (const float*)d_in[9];  const float* b_q  = (const float*)d_in[10];
  const float* W_k  = (const float*)d_in[11]; const float* b_k  = (const float*)d_in[12];
  const float* W_v  = (const float*)d_in[13]; const float* b_v  = (const float*)d_in[14];
  const float* W_o  = (const float*)d_in[15]; const float* b_o  = (const float*)d_in[16];
  const float* W_m1 = (const float*)d_in[17]; const float* b_m1 = (const float*)d_in[18];
  const float* W_m2 = (const float*)d_in[19]; const float* b_m2 = (const float*)d_in[20];

  char* ws = (char*)d_ws;
  short* Wbf  = (short*)ws;                                   // 786,432 B (6 x 64K bf16)
  short* n1   = (short*)(ws + 786432);                        // 16.78 MB: q_in -> ctx -> h1
  short* n2   = (short*)(ws + 786432 + 16777216);             // 16.78 MB: Q -> h_ln
  short* kvin = (short*)(ws + 786432 + 2 * 16777216);         // 1 MB
  short* Kb   = (short*)(ws + 786432 + 2 * 16777216 + 1048576);
  short* vt   = (short*)(ws + 786432 + 2 * 16777216 + 2 * 1048576);  // V^T [B][H][64][256]

  float* xbuf = (float*)d_out;            // first half: x, later overwritten by final out
  float* amof = (float*)d_out + 8388608;  // second half: attn_matrix

  cvt_w<<<1536, 256, 0, stream>>>(W_q, W_k, W_v, W_o, W_m1, W_m2, Wbf);
  ln_k<<<32768, 256, 0, stream>>>(node_emb, ln_q_g, ln_q_b, n1);
  ln_k<<<2048, 256, 0, stream>>>(cluster, ln_kv_g, ln_kv_b, kvin);
  // Q / K / V projections (V written transposed into vt)
  gemm256<0,0,0,1,0><<<dim3(512, 4), 256, 0, stream>>>(n1,   Wbf,          b_q, nullptr, nullptr, n2);
  gemm256<0,0,0,1,0><<<dim3(32, 4),  256, 0, stream>>>(kvin, Wbf + 65536,  b_k, nullptr, nullptr, Kb);
  gemm256<0,0,0,1,1><<<dim3(32, 4),  256, 0, stream>>>(kvin, Wbf + 131072, b_v, nullptr, nullptr, vt);
  // attention (ctx -> n1, attn_matrix -> d_out 2nd half)
  attn_k<<<dim3(64, 8), 256, 0, stream>>>(n2, Kb, vt, cw, n1, amof);
  // O proj + residual -> x (f32, in d_out first half)
  gemm256<1,0,1,0,0><<<dim3(512, 4), 256, 0, stream>>>(n1, Wbf + 196608, b_o, node_emb, xbuf, nullptr);
  // LN(x) -> h_ln (bf16 in n2)
  ln_k<<<32768, 256, 0, stream>>>(xbuf, ln_o_g, ln_o_b, n2);
  // MLP1 + GELU -> n1 ; MLP2 + residual(x) -> final out (in-place over x)
  gemm256<0,1,0,1,0><<<dim3(512, 4), 256, 0, stream>>>(n2, Wbf + 262144, b_m1, nullptr, nullptr, n1);
  gemm256<1,0,1,0,0><<<dim3(512, 4), 256, 0, stream>>>(n1, Wbf + 327680, b_m2, xbuf, xbuf, nullptr);
}

// Round 3
// 173.961 us; speedup vs baseline: 3.1989x; 1.1084x over previous
//
#include <hip/hip_runtime.h>
#include <math.h>

typedef __attribute__((ext_vector_type(8))) short short8;
typedef __attribute__((ext_vector_type(4))) float f32x4;

__device__ __forceinline__ float b2f(short s){
  return __uint_as_float(((unsigned int)(unsigned short)s) << 16);
}
__device__ __forceinline__ short f2b(float f){
  unsigned int u = __float_as_uint(f);
  u = (u + 0x7fffu + ((u >> 16) & 1u)) >> 16;
  return (short)u;
}
__device__ __forceinline__ unsigned pk2(float lo, float hi){
  return ((unsigned)(unsigned short)f2b(hi) << 16) | (unsigned)(unsigned short)f2b(lo);
}

// ---------------- weight f32 -> bf16 conversion ----------------
__global__ __launch_bounds__(256) void cvt_w(
    const float* __restrict__ s0, const float* __restrict__ s1,
    const float* __restrict__ s2, const float* __restrict__ s3,
    const float* __restrict__ s4, const float* __restrict__ s5,
    short* __restrict__ dst)
{
  const float* srcs[6] = {s0, s1, s2, s3, s4, s5};
  int i = blockIdx.x * 256 + threadIdx.x;       // 6*65536 total
  dst[i] = f2b(srcs[i >> 16][i & 65535]);
}

// ---------------- LayerNorm: f32 in, bf16 out ----------------
__global__ __launch_bounds__(256) void ln_k(
    const float* __restrict__ x, const float* __restrict__ g,
    const float* __restrict__ bta, short* __restrict__ y)
{
  const int row = blockIdx.x, t = threadIdx.x;
  const size_t base = (size_t)row * 256;
  float v = x[base + t];
  float s1 = v, s2 = v * v;
  #pragma unroll
  for (int off = 32; off; off >>= 1){ s1 += __shfl_down(s1, off); s2 += __shfl_down(s2, off); }
  __shared__ float a1[4], a2[4];
  __shared__ float mu_s, rs_s;
  if ((t & 63) == 0){ a1[t >> 6] = s1; a2[t >> 6] = s2; }
  __syncthreads();
  if (t == 0){
    float S1 = a1[0] + a1[1] + a1[2] + a1[3];
    float S2 = a2[0] + a2[1] + a2[2] + a2[3];
    float mu = S1 * 0.00390625f;
    float var = S2 * 0.00390625f - mu * mu;
    mu_s = mu; rs_s = rsqrtf(var + 1e-5f);
  }
  __syncthreads();
  y[base + t] = f2b((v - mu_s) * rs_s * g[t] + bta[t]);
}

// ---------------- GEMM: C[M,256] = A[M,256] @ W[256,256]^T + b ----------------
// A, W bf16 (W in [N][K] layout). f32 accum via MFMA.
// Epilogue: optional GELU, f32 residual, f32/bf16 out, OT = bf16 out transposed
// into Vt layout with kv-permuted columns (for the attn PV register path):
//   col' = (j&~31) | (((j>>2)&3)<<3) | (((j>>4)&1)<<2) | (j&3),  j = m&255
template<int RES, int GELU, int OF, int OB, int OT>
__global__ __launch_bounds__(256) void gemm256(
    const short* __restrict__ A, const short* __restrict__ W,
    const float* __restrict__ bias, const float* __restrict__ res,
    float* __restrict__ outF, short* __restrict__ outB)
{
  __shared__ short As[64][48];   // pad to 48 (96B rows, 16B aligned)
  __shared__ short Ws[64][48];
  const int tid = threadIdx.x;
  const int m0 = blockIdx.x << 6;
  const int n0 = blockIdx.y << 6;
  const int wave = tid >> 6, lane = tid & 63;
  const int sr = tid >> 2, sc = (tid & 3) << 3;
  const int fr = lane & 15, fk = (lane >> 4) << 3;
  f32x4 acc[4] = {{0,0,0,0},{0,0,0,0},{0,0,0,0},{0,0,0,0}};
  for (int k0 = 0; k0 < 256; k0 += 32){
    if (k0) __syncthreads();
    *(short8*)&As[sr][sc] = *(const short8*)&A[(size_t)(m0 + sr) * 256 + k0 + sc];
    *(short8*)&Ws[sr][sc] = *(const short8*)&W[(size_t)(n0 + sr) * 256 + k0 + sc];
    __syncthreads();
    short8 af = *(const short8*)&As[(wave << 4) + fr][fk];
    #pragma unroll
    for (int nt = 0; nt < 4; ++nt){
      short8 bf = *(const short8*)&Ws[(nt << 4) + fr][fk];
      acc[nt] = __builtin_amdgcn_mfma_f32_16x16x32_bf16(af, bf, acc[nt], 0, 0, 0);
    }
  }
  const int r0 = (wave << 4) + ((lane >> 4) << 2);
  #pragma unroll
  for (int nt = 0; nt < 4; ++nt){
    const int n = n0 + (nt << 4) + fr;
    const float bv = bias[n];
    #pragma unroll
    for (int r = 0; r < 4; ++r){
      const int m = m0 + r0 + r;
      const size_t idx = (size_t)m * 256 + n;
      float v = acc[nt][r] + bv;
      if (GELU) v = 0.5f * v * (1.0f + erff(v * 0.70710678118f));
      if (RES) v += res[idx];
      if (OF) outF[idx] = v;
      if (OB){
        if (OT){
          const int j = m & 255;
          const int jp = (j & ~31) | (((j >> 2) & 3) << 3) | (((j >> 4) & 1) << 2) | (j & 3);
          outB[(size_t)((m & ~255) | n) * 256 + jp] = f2b(v);
        } else {
          outB[idx] = f2b(v);
        }
      }
    }
  }
}

// ---------------- fused MFMA attention (P in registers) ----------------
// Block: 64 q-rows, 4 waves (16 rows each), all 4 heads.
// Swapped QK^T: acc = mfma(K_frag, Q_frag) -> lane(l15,g) holds
// P[q = l15][kv = 16*nt + 4*g + r]  (full kv row lane-local across nt,r).
// Softmax fully in-register; PV uses kv-permuted Vt so A-frags are in-lane packs.
__global__ __launch_bounds__(256, 2) void attn_k(
    const short* __restrict__ Qb, const short* __restrict__ Kb,
    const short* __restrict__ Vtg, const float* __restrict__ cw,
    short* __restrict__ ctx, float* __restrict__ am_out)
{
  __shared__ short Kp[256][80];   // stride 160B: 4-way dword aliasing max
  __shared__ short Vt[64][272];   // stride 544B: 4-way
  const int b = blockIdx.y;
  const int q0 = blockIdx.x << 6;
  const int tid = threadIdx.x;
  const int w = tid >> 6, lane = tid & 63;
  const int l15 = lane & 15, g = lane >> 4;
  const size_t qw = (size_t)b * 4096 + q0 + (w << 4);   // wave's first q row

  // clustering weights (bf16-packed) + attn_matrix accumulator, in registers.
  // element (nt, r) <-> cw[(qw + l15)*256 + 16*nt + 4*g + r]
  unsigned cwp[16][2];
  f32x4 am[16];
  #pragma unroll
  for (int nt = 0; nt < 16; ++nt){
    f32x4 c = *(const f32x4*)&cw[(qw + l15) * 256 + (nt << 4) + (g << 2)];
    cwp[nt][0] = pk2(c[0], c[1]);
    cwp[nt][1] = pk2(c[2], c[3]);
    am[nt] = {0.f, 0.f, 0.f, 0.f};
  }

  for (int h = 0; h < 4; ++h){
    __syncthreads();                       // Kp/Vt free from prior head
    #pragma unroll
    for (int it = 0; it < 8; ++it){        // stage K_h (true kv order)
      int idx = tid + (it << 8);
      int row = idx >> 3, c0 = (idx & 7) << 3;
      *(short8*)&Kp[row][c0] = *(const short8*)&Kb[((size_t)(b * 256 + row) << 8) + (h << 6) + c0];
    }
    #pragma unroll
    for (int it = 0; it < 8; ++it){        // stage Vt_h (cols pre-permuted in global)
      int idx = tid + (it << 8);
      int row = idx >> 5, c0 = (idx & 31) << 3;
      *(short8*)&Vt[row][c0] = *(const short8*)&Vtg[((size_t)(b * 256 + (h << 6) + row) << 8) + c0];
    }
    // Q B-fragments straight from global (L2); latency hidden under the barrier drain
    short8 qf0 = *(const short8*)&Qb[(qw + l15) * 256 + (h << 6) + (g << 3)];
    short8 qf1 = *(const short8*)&Qb[(qw + l15) * 256 + (h << 6) + 32 + (g << 3)];
    __syncthreads();

    // ---- scores: swapped operands ----
    f32x4 acc[16];
    #pragma unroll
    for (int nt = 0; nt < 16; ++nt) acc[nt] = {0.f, 0.f, 0.f, 0.f};
    #pragma unroll
    for (int nt = 0; nt < 16; ++nt){
      short8 kf0 = *(const short8*)&Kp[(nt << 4) + l15][(g << 3)];
      acc[nt] = __builtin_amdgcn_mfma_f32_16x16x32_bf16(kf0, qf0, acc[nt], 0, 0, 0);
      short8 kf1 = *(const short8*)&Kp[(nt << 4) + l15][32 + (g << 3)];
      acc[nt] = __builtin_amdgcn_mfma_f32_16x16x32_bf16(kf1, qf1, acc[nt], 0, 0, 0);
    }
    // ---- softmax, fully in-lane (row q = l15; partners at lane^16, lane^32) ----
    float mx = -3.4e38f;
    #pragma unroll
    for (int nt = 0; nt < 16; ++nt){
      float c0 = __uint_as_float(cwp[nt][0] << 16);
      float c1 = __uint_as_float(cwp[nt][0] & 0xffff0000u);
      float c2 = __uint_as_float(cwp[nt][1] << 16);
      float c3 = __uint_as_float(cwp[nt][1] & 0xffff0000u);
      acc[nt][0] = acc[nt][0] * 0.125f + c0;
      acc[nt][1] = acc[nt][1] * 0.125f + c1;
      acc[nt][2] = acc[nt][2] * 0.125f + c2;
      acc[nt][3] = acc[nt][3] * 0.125f + c3;
      mx = fmaxf(mx, fmaxf(fmaxf(acc[nt][0], acc[nt][1]), fmaxf(acc[nt][2], acc[nt][3])));
    }
    mx = fmaxf(mx, __shfl_xor(mx, 16));
    mx = fmaxf(mx, __shfl_xor(mx, 32));
    float sm = 0.f;
    #pragma unroll
    for (int nt = 0; nt < 16; ++nt){
      #pragma unroll
      for (int r = 0; r < 4; ++r){
        float e = __expf(acc[nt][r] - mx);
        acc[nt][r] = e; sm += e;
      }
    }
    sm += __shfl_xor(sm, 16);
    sm += __shfl_xor(sm, 32);
    float inv = 1.f / sm;
    #pragma unroll
    for (int nt = 0; nt < 16; ++nt){
      #pragma unroll
      for (int r = 0; r < 4; ++r){
        float p = acc[nt][r] * inv;
        acc[nt][r] = p;
        am[nt][r] += 0.25f * p;
      }
    }
    // ---- ctx = P @ V : A-frags are in-lane packs (kv-permuted Vt cols match) ----
    f32x4 oc[4] = {{0,0,0,0},{0,0,0,0},{0,0,0,0},{0,0,0,0}};
    #pragma unroll
    for (int kk = 0; kk < 8; ++kk){
      union { short8 s; unsigned u[4]; } pa;
      pa.u[0] = pk2(acc[2 * kk][0],     acc[2 * kk][1]);
      pa.u[1] = pk2(acc[2 * kk][2],     acc[2 * kk][3]);
      pa.u[2] = pk2(acc[2 * kk + 1][0], acc[2 * kk + 1][1]);
      pa.u[3] = pk2(acc[2 * kk + 1][2], acc[2 * kk + 1][3]);
      #pragma unroll
      for (int n2 = 0; n2 < 4; ++n2){
        short8 vb = *(const short8*)&Vt[(n2 << 4) + l15][(kk << 5) + (g << 3)];
        oc[n2] = __builtin_amdgcn_mfma_f32_16x16x32_bf16(pa.s, vb, oc[n2], 0, 0, 0);
      }
    }
    // lane holds ctx[q = 4g + r][d = 16*n2 + l15]
    #pragma unroll
    for (int n2 = 0; n2 < 4; ++n2)
      #pragma unroll
      for (int r = 0; r < 4; ++r)
        ctx[((size_t)b * 4096 + q0 + (w << 4) + (g << 2) + r) * 256 + (h << 6) + (n2 << 4) + l15]
            = f2b(oc[n2][r]);
  }
  #pragma unroll
  for (int nt = 0; nt < 16; ++nt)
    *(f32x4*)&am_out[(qw + l15) * 256 + (nt << 4) + (g << 2)] = am[nt];
}

extern "C" void kernel_launch(void* const* d_in, const int* in_sizes, int n_in,
                              void* d_out, int out_size, void* d_ws, size_t ws_size,
                              hipStream_t stream)
{
  const float* node_emb = (const float*)d_in[0];
  const float* cluster  = (const float*)d_in[1];
  const float* cw       = (const float*)d_in[2];
  const float* ln_q_g   = (const float*)d_in[3];
  const float* ln_q_b   = (const float*)d_in[4];
  const float* ln_kv_g  = (const float*)d_in[5];
  const float* ln_kv_b  = (const float*)d_in[6];
  const float* ln_o_g   = (const float*)d_in[7];
  const float* ln_o_b   = (const float*)d_in[8];
  const float* W_q  = (const float*)d_in[9];  const float* b_q  = (const float*)d_in[10];
  const float* W_k  = (const float*)d_in[11]; const float* b_k  = (const float*)d_in[12];
  const float* W_v  = (const float*)d_in[13]; const float* b_v  = (const float*)d_in[14];
  const float* W_o  = (const float*)d_in[15]; const float* b_o  = (const float*)d_in[16];
  const float* W_m1 = (const float*)d_in[17]; const float* b_m1 = (const float*)d_in[18];
  const float* W_m2 = (const float*)d_in[19]; const float* b_m2 = (const float*)d_in[20];

  char* ws = (char*)d_ws;
  short* Wbf  = (short*)ws;                                   // 786,432 B (6 x 64K bf16)
  short* n1   = (short*)(ws + 786432);                        // 16.78 MB: q_in -> ctx -> h1
  short* n2   = (short*)(ws + 786432 + 16777216);             // 16.78 MB: Q -> h_ln
  short* kvin = (short*)(ws + 786432 + 2 * 16777216);         // 1 MB
  short* Kb   = (short*)(ws + 786432 + 2 * 16777216 + 1048576);
  short* vt   = (short*)(ws + 786432 + 2 * 16777216 + 2 * 1048576);  // V^T, kv-permuted cols

  float* xbuf = (float*)d_out;            // first half: x, later overwritten by final out
  float* amof = (float*)d_out + 8388608;  // second half: attn_matrix

  cvt_w<<<1536, 256, 0, stream>>>(W_q, W_k, W_v, W_o, W_m1, W_m2, Wbf);
  ln_k<<<32768, 256, 0, stream>>>(node_emb, ln_q_g, ln_q_b, n1);
  ln_k<<<2048, 256, 0, stream>>>(cluster, ln_kv_g, ln_kv_b, kvin);
  // Q / K / V projections (V written transposed + kv-permuted into vt)
  gemm256<0,0,0,1,0><<<dim3(512, 4), 256, 0, stream>>>(n1,   Wbf,          b_q, nullptr, nullptr, n2);
  gemm256<0,0,0,1,0><<<dim3(32, 4),  256, 0, stream>>>(kvin, Wbf + 65536,  b_k, nullptr, nullptr, Kb);
  gemm256<0,0,0,1,1><<<dim3(32, 4),  256, 0, stream>>>(kvin, Wbf + 131072, b_v, nullptr, nullptr, vt);
  // attention (ctx -> n1, attn_matrix -> d_out 2nd half)
  attn_k<<<dim3(64, 8), 256, 0, stream>>>(n2, Kb, vt, cw, n1, amof);
  // O proj + residual -> x (f32, in d_out first half)
  gemm256<1,0,1,0,0><<<dim3(512, 4), 256, 0, stream>>>(n1, Wbf + 196608, b_o, node_emb, xbuf, nullptr);
  // LN(x) -> h_ln (bf16 in n2)
  ln_k<<<32768, 256, 0, stream>>>(xbuf, ln_o_g, ln_o_b, n2);
  // MLP1 + GELU -> n1 ; MLP2 + residual(x) -> final out (in-place over x)
  gemm256<0,1,0,1,0><<<dim3(512, 4), 256, 0, stream>>>(n2, Wbf + 262144, b_m1, nullptr, nullptr, n1);
  gemm256<1,0,1,0,0><<<dim3(512, 4), 256, 0, stream>>>(n1, Wbf + 327680, b_m2, xbuf, xbuf, nullptr);
}